// Round 3
// baseline (239.117 us; speedup 1.0000x reference)
//
#include <hip/hip_runtime.h>
#include <math.h>

#define ALPHA  0.1f
#define DT     0.01f
#define EPSV   1e-9f
#define DIFF   10.0f
#define HARD_P 1.5707963267948966f

// Kernel 1: per-node precompute.
//   g[i] = e^{-i*phase[i]} * (x_i + i*y_i)
//   out[3N:5N] = xy  (xy_dot_old_new)
//   rowptr[i] = lower_bound(edge_src, i)   (edge_src is sorted)
__global__ void node_pre(const float2* __restrict__ xy,
                         const float*  __restrict__ phase,
                         const int*    __restrict__ src,
                         float2* __restrict__ g,
                         float2* __restrict__ out_xyold,
                         int*    __restrict__ rowptr,
                         int n, int n_edges) {
    int i = blockIdx.x * blockDim.x + threadIdx.x;
    if (i >= n) return;
    float2 p = xy[i];
    float ph = phase[i];
    float s, c;
    sincosf(ph, &s, &c);
    float2 gv;
    gv.x = p.x * c + p.y * s;   // e^{-i ph} * (x + iy)
    gv.y = p.y * c - p.x * s;
    g[i] = gv;
    out_xyold[i] = p;

    // lower_bound: first e with src[e] >= i
    int lo = 0, hi = n_edges;
    while (lo < hi) {
        int mid = (lo + hi) >> 1;
        if (src[mid] < i) lo = mid + 1; else hi = mid;
    }
    rowptr[i] = lo;
    if (i == 0) rowptr[n] = n_edges;
}

// Kernel 2: one 64-lane wave per node. Coalesced dst reads, independent
// L2 gathers of g[dst], butterfly reduce, lane 0 does node dynamics +
// writes all outputs. No atomics.
__global__ __launch_bounds__(256) void node_sum_post(
        const int*    __restrict__ rowptr,
        const int*    __restrict__ dst,
        const float2* __restrict__ g,
        const float2* __restrict__ xy,
        const float2* __restrict__ xyd,
        const float*  __restrict__ phase,
        const float*  __restrict__ w,
        const float*  __restrict__ amps,
        const float*  __restrict__ ha,
        float* __restrict__ out,
        int n) {
    const int lane = threadIdx.x & 63;
    const int wid  = threadIdx.x >> 6;
    const int node = blockIdx.x * (blockDim.x >> 6) + wid;
    if (node >= n) return;

    const int e0 = rowptr[node];
    const int e1 = rowptr[node + 1];

    float ax = 0.f, ay = 0.f;
    for (int e = e0 + lane; e < e1; e += 64) {
        int d = dst[e];          // coalesced across lanes
        float2 gd = g[d];        // L2-resident gather, 1 per lane in flight
        ax += gd.x; ay += gd.y;
    }
    // 64-lane butterfly reduction
    #pragma unroll
    for (int off = 32; off > 0; off >>= 1) {
        ax += __shfl_xor(ax, off);
        ay += __shfl_xor(ay, off);
    }

    if (lane == 0) {
        float2 p   = xy[node];
        float2 pdv = xyd[node];
        float x = p.x, y = p.y;
        float xd = pdv.x, yd = pdv.y;

        float r2 = x*x + y*y;
        float a = ALPHA * (1.0f - r2*r2);
        float h = ha[node];
        float zeta = 1.0f - h * ((xd + EPSV) / (fabsf(xd) + EPSV));
        float b = w[node] / (zeta + EPSV);
        float kx = a*x - b*y;
        float ky = b*x + a*y;

        float s, c;
        sincosf(phase[node], &s, &c);
        float sumx = c*ax - s*ay;   // rotate by e^{+i*phase}
        float sumy = s*ax + c*ay;

        float xdot = fminf(fmaxf(kx + sumx, xd - DIFF), xd + DIFF);
        float ydot = fminf(fmaxf(ky + sumy, yd - DIFF), yd + DIFF);
        float xn = x + xdot * DT;
        float yn = y + ydot * DT;

        float ang = fminf(fmaxf(amps[node] * yn, -HARD_P), HARD_P);

        out[node] = ang;
        float2* xy_new = (float2*)(out + n);
        float2 v; v.x = xn; v.y = yn;
        xy_new[node] = v;
    }
}

extern "C" void kernel_launch(void* const* d_in, const int* in_sizes, int n_in,
                              void* d_out, int out_size, void* d_ws, size_t ws_size,
                              hipStream_t stream) {
    const float2* xy    = (const float2*)d_in[0];
    const float2* xyd   = (const float2*)d_in[1];
    const float*  phase = (const float*)d_in[2];
    const float*  w     = (const float*)d_in[3];
    const float*  amps  = (const float*)d_in[4];
    const float*  ha    = (const float*)d_in[5];
    const int*    esrc  = (const int*)d_in[6];
    const int*    edst  = (const int*)d_in[7];

    const int n       = in_sizes[2];
    const int n_edges = in_sizes[6];

    float* out = (float*)d_out;

    // workspace: g (float2[n]) | rowptr (int[n+1])
    float2* g      = (float2*)d_ws;
    int*    rowptr = (int*)((char*)d_ws + (size_t)n * sizeof(float2));

    const int B = 256;
    node_pre<<<(n + B - 1) / B, B, 0, stream>>>(
        xy, phase, esrc, g, (float2*)(out + (size_t)3 * n), rowptr, n, n_edges);

    const int nodes_per_block = B / 64;   // 4 waves per block, 1 node each
    node_sum_post<<<(n + nodes_per_block - 1) / nodes_per_block, B, 0, stream>>>(
        rowptr, edst, g, xy, xyd, phase, w, amps, ha, out, n);
}